// Round 21
// baseline (220.259 us; speedup 1.0000x reference)
//
#include <hip/hip_runtime.h>

#define NN 100000
#define NE 1600000
#define DIM 64
#define NR 391      // regions = ceil(NN/256), key = dst>>8
#define BP 400      // partition blocks, 4000 edges each
#define MH (NR * BP)  // 156400 histogram cells, r-major
#define NSB2 611    // ceil(MH/256)
#define TROWS 48    // nodes per tile: grid 2084 -> 8.1 blocks/CU -> 32-wave cap
#define NTIL 2084   // ceil(NN/48)
#define IDXCAP 1280 // staged edge cap per 48-node tile (mean 768, 18 sigma)
#define DUMMY (48u << 17)  // pad edge: src 0 (valid row), target scrap row 48

typedef unsigned short u16;
typedef unsigned int u32;
typedef __attribute__((ext_vector_type(8))) short short8;  // 8 bf16 (4 VGPRs)
typedef __attribute__((ext_vector_type(4))) float f32x4;

__device__ __forceinline__ u16 f2b(float f) {  // f32 -> bf16 RNE
  union { float f; u32 u; } c; c.f = f;
  u32 u = c.u;
  u += 0x7FFF + ((u >> 16) & 1);
  return (u16)(u >> 16);
}
__device__ __forceinline__ float blo(u32 v) {
  union { u32 u; float f; } c; c.u = v << 16;
  return c.f;
}
__device__ __forceinline__ float bhi(u32 v) {
  union { u32 u; float f; } c; c.u = v & 0xFFFF0000u;
  return c.f;
}
__device__ __forceinline__ u32 pk(float lo, float hi) {  // pack 2 bf16
  return ((u32)f2b(hi) << 16) | (u32)f2b(lo);
}

union FragU { u32 w[4]; short8 v; };

// x (f32) -> xh (bf16), 4 elems/thread, exact grid
__global__ __launch_bounds__(256) void k_tobf(const float* __restrict__ x,
                                              u16* __restrict__ xh) {
  int i = blockIdx.x * 256 + threadIdx.x;
  float4 v = ((const float4*)x)[i];
  ushort4 o;
  o.x = f2b(v.x); o.y = f2b(v.y); o.z = f2b(v.z); o.w = f2b(v.w);
  ((ushort4*)xh)[i] = o;
}

// convert 7 64x64 f32 weights ([k][j] k-major) -> bf16-packed transposed
// wt[m][j][kk] : u32 = {k=2kk (lo), k=2kk+1 (hi)} at column j.
__global__ __launch_bounds__(256) void k_wconv(const float* __restrict__ W1,
                                               const float* __restrict__ W2,
                                               const float* __restrict__ Wf,
                                               u32* __restrict__ wt) {
  int m = blockIdx.x;
  const float* src = (m < 3) ? (W1 + m * 4096) : (m < 6 ? (W2 + (m - 3) * 4096) : Wf);
  for (int c = threadIdx.x; c < 2048; c += 256) {
    int j = c >> 5, kk = c & 31;
    wt[m * 2048 + c] = pk(src[(2 * kk) * 64 + j], src[(2 * kk + 1) * 64 + j]);
  }
}

// ---- deterministic two-pass region partition (no global data atomics) ----

__global__ __launch_bounds__(256) void k_phist(const int* __restrict__ ei,
                                               int* __restrict__ Hmat) {
  __shared__ int lh[NR];
  const int t = threadIdx.x;
  const int b = blockIdx.x;
  for (int i = t; i < NR; i += 256) lh[i] = 0;
  __syncthreads();
  const int e0 = b * 4000;
  for (int k = 0; k < 16; ++k) {
    int o = k * 256 + t;
    if (o < 4000) atomicAdd(&lh[ei[NE + e0 + o] >> 8], 1);
  }
  __syncthreads();
  for (int i = t; i < NR; i += 256) Hmat[i * BP + b] = lh[i];
}

__global__ __launch_bounds__(256) void k_sA(int* __restrict__ a,
                                            int* __restrict__ bsum) {
  __shared__ int buf[256];
  const int t = threadIdx.x;
  const int i = blockIdx.x * 256 + t;
  int v = (i < MH) ? a[i] : 0;
  buf[t] = v;
  __syncthreads();
  for (int off = 1; off < 256; off <<= 1) {
    int u = (t >= off) ? buf[t - off] : 0;
    __syncthreads();
    buf[t] += u;
    __syncthreads();
  }
  if (i < MH) a[i] = buf[t] - v;
  if (t == 255) bsum[blockIdx.x] = buf[255];
}

__global__ __launch_bounds__(1024) void k_sB(int* __restrict__ bsum) {
  __shared__ int buf[1024];
  const int t = threadIdx.x;
  int v = (t < NSB2) ? bsum[t] : 0;
  buf[t] = v;
  __syncthreads();
  for (int off = 1; off < 1024; off <<= 1) {
    int u = (t >= off) ? buf[t - off] : 0;
    __syncthreads();
    buf[t] += u;
    __syncthreads();
  }
  if (t < NSB2) bsum[t] = buf[t] - v;
}

__global__ __launch_bounds__(256) void k_sC(int* __restrict__ a,
                                            const int* __restrict__ bsum) {
  int i = blockIdx.x * 256 + threadIdx.x;
  if (i < MH) a[i] += bsum[blockIdx.x];
}

__global__ __launch_bounds__(512) void k_rex(const int* __restrict__ Hs,
                                             int* __restrict__ rstart,
                                             int* __restrict__ nstartP) {
  int t = threadIdx.x;
  if (t < NR) rstart[t] = Hs[t * BP];
  if (t == 0) { rstart[NR] = NE; nstartP[NN] = NE; }
}

__global__ __launch_bounds__(256) void k_pfill(const int* __restrict__ ei,
                                               const int* __restrict__ Hs,
                                               int* __restrict__ bb) {
  __shared__ int lcur[NR];
  const int t = threadIdx.x;
  const int b = blockIdx.x;
  for (int i = t; i < NR; i += 256) lcur[i] = Hs[i * BP + b];
  __syncthreads();
  const int e0 = b * 4000;
  for (int k = 0; k < 16; ++k) {
    int o = k * 256 + t;
    if (o < 4000) {
      int e = e0 + o;
      int src = ei[e];
      int dst = ei[NE + e];
      int p = atomicAdd(&lcur[dst >> 8], 1);  // LDS atomic only
      bb[p] = src | ((dst & 255) << 17);      // src < 2^17
    }
  }
}

// counting-sort by node -> csr2 entries = src | ((node % 48) << 17)
// (48-node tiles: tag = node-in-tile; tiles don't align with regions, so
//  compute from the global node id)
__global__ __launch_bounds__(256) void k_rsort(const int* __restrict__ rstart,
                                               const int* __restrict__ bb,
                                               int* __restrict__ csr2,
                                               int* __restrict__ nstartP) {
  __shared__ int nhist[256], ncur[256], buf[256];
  const int t = threadIdx.x;
  const int r = blockIdx.x;
  const int s = rstart[r];
  const int cnt = rstart[r + 1] - s;
  const int nb = r << 8;
  nhist[t] = 0;
  __syncthreads();
  for (int p = t; p < cnt; p += 256) atomicAdd(&nhist[bb[s + p] >> 17], 1);
  __syncthreads();
  int v = nhist[t];
  buf[t] = v;
  __syncthreads();
  for (int off = 1; off < 256; off <<= 1) {
    int u = (t >= off) ? buf[t - off] : 0;
    __syncthreads();
    buf[t] += u;
    __syncthreads();
  }
  int st = s + buf[t] - v;
  ncur[t] = st;
  if (nb + t < NN) nstartP[nb + t] = st;
  __syncthreads();
  for (int p = t; p < cnt; p += 256) {
    int e2 = bb[s + p];
    int loc = e2 >> 17;             // node-in-region 0..255
    u32 g = (u32)(nb + loc);        // global node
    u32 tag = g - 48u * (g / 48u);  // node-in-tile 0..47 (const-div)
    int pos = atomicAdd(&ncur[loc], 1);
    csr2[pos] = (e2 & 0x1FFFF) | ((int)tag << 17);
  }
}

// one 16x16x64 GEMM slice: wave's M-stripe x all 64 cols. A from packed LDS
// (u32 stride 33); B from bf16-packed transposed wt.
__device__ __forceinline__ void mfma_gemm(const u32* T32, const u32* __restrict__ wt,
                                          int wvv, int lr, int lg, f32x4 acc[4]) {
  FragU a0, a1;
  const int abase = (16 * wvv + lr) * 33 + 4 * lg;
#pragma unroll
  for (int c = 0; c < 4; ++c) { a0.w[c] = T32[abase + c]; a1.w[c] = T32[abase + 16 + c]; }
#pragma unroll
  for (int t = 0; t < 4; ++t) {
    FragU b0, b1;
    const u32* wp = wt + (16 * t + lr) * 32 + 4 * lg;
#pragma unroll
    for (int c = 0; c < 4; ++c) { b0.w[c] = wp[c]; b1.w[c] = wp[16 + c]; }
    acc[t] = __builtin_amdgcn_mfma_f32_16x16x32_bf16(a0.v, b0.v, acc[t], 0, 0, 0);
    acc[t] = __builtin_amdgcn_mfma_f32_16x16x32_bf16(a1.v, b1.v, acc[t], 0, 0, 0);
  }
}

// relu + pack D frags (col=lane&15, row=4*(lane>>4)+r) back into packed words
__device__ __forceinline__ void pack_relu(u32* T32, int wvv, int lr, int lg,
                                          const f32x4 acc[4]) {
#pragma unroll
  for (int t = 0; t < 4; ++t)
#pragma unroll
    for (int r = 0; r < 4; ++r) {
      float v = fmaxf(acc[t][r], 0.0f);
      float p = __shfl_xor(v, 1, 64);  // partner holds col^1, same rows
      if ((lr & 1) == 0)
        T32[(16 * wvv + 4 * lg + r) * 33 + 8 * t + (lr >> 1)] = pk(v, p);
    }
}

// load a 16-edge chunk: tags from staged LDS (DUMMY past end), then issue
// all 16 row-loads. Named register arrays, fully unrolled (static indexing).
#define LOADCHUNK(EV, VV, P0)                              \
  _Pragma("unroll")                                        \
  for (int i_ = 0; i_ < 16; ++i_) {                        \
    int p_ = (P0) + i_;                                    \
    EV[i_] = (p_ < ge) ? (u32)sidx[p_] : DUMMY;            \
  }                                                        \
  _Pragma("unroll")                                        \
  for (int i_ = 0; i_ < 16; ++i_)                          \
    VV[i_] = xu[(size_t)(EV[i_] & 0x1FFFF) * 32 + fl];

// flush: tile word = pk(sc*self + acc). One flush per node (sorted slice),
// so OVERWRITE with the full f32 sum.
#define FLUSH(CUR)                                          \
  {                                                         \
    float s0_ = 0.f, s1_ = 0.f;                             \
    if ((CUR) < rows) {                                     \
      u32 su_ = xu[(size_t)(base + (CUR)) * 32 + fl];       \
      s0_ = sc * blo(su_); s1_ = sc * bhi(su_);             \
    }                                                       \
    tile32[(CUR) * 33 + fl] = pk(s0_ + a0, s1_ + a1);       \
  }

#define PROCCHUNK(EV, VV)                                  \
  _Pragma("unroll")                                        \
  for (int i_ = 0; i_ < 16; ++i_) {                        \
    int n_ = (int)(EV[i_] >> 17);                          \
    if (n_ != cur) {                                       \
      FLUSH(cur)                                           \
      cur = n_; a0 = 0.f; a1 = 0.f;                        \
    }                                                      \
    a0 += blo(VV[i_]); a1 += bhi(VV[i_]);                  \
  }

// ---- fused layer (48-node tile): segmented flat-edge gather (register
//      accumulation, one packed-bf16 flush per node) -> barrier -> MFMA MLP
//      on 3 stripes (+ fused final). Grid 2084 -> full 32-wave/CU cap. ----
template <int FINAL>
__global__ __launch_bounds__(256, 8) void k_gin(const u16* __restrict__ xh,
                                                const int* __restrict__ nstartP,
                                                const int* __restrict__ csr2,
                                                const float* __restrict__ eps, int l,
                                                const u32* __restrict__ wt1,
                                                const float* __restrict__ b1,
                                                const u32* __restrict__ wt2,
                                                const float* __restrict__ b2,
                                                u16* __restrict__ outh,
                                                const u32* __restrict__ wtf,
                                                const float* __restrict__ bf,
                                                float* __restrict__ outf) {
  __shared__ u32 tile32[49 * 33];  // packed bf16 pairs; row 48 = scrap
  __shared__ int sidx[IDXCAP];
  __shared__ int sstart[9];        // 6-node slice boundaries
  const int tid = threadIdx.x;
  const int lane = tid & 63;
  const int wvv = tid >> 6;  // 0..3
  const int h = lane >> 5;
  const int fl = lane & 31;
  const int base = blockIdx.x * TROWS;
  const int rows = min(TROWS, NN - base);
  const float sc = 1.0f + eps[l];
  const u32* xu = (const u32*)xh;

  const int s0 = nstartP[base];
  const int cnt = nstartP[min(base + TROWS, NN)] - s0;
  if (tid < 9) sstart[tid] = nstartP[min(base + 6 * tid, NN)];
  const bool fast = (cnt <= IDXCAP);

  // init: tile word = pk(sc*self) for rows < rows, else 0. 48*32 = 1536 cells.
#pragma unroll
  for (int c = 0; c < 6; ++c) {
    int cell = c * 256 + tid;  // 0..1535
    int row = cell >> 5, f = cell & 31;
    u32 w = 0;
    if (row < rows) {
      u32 u_ = xu[(size_t)(base + row) * 32 + f];
      w = pk(sc * blo(u_), sc * bhi(u_));
    }
    tile32[row * 33 + f] = w;
  }
  if (fast)
    for (int p = tid; p < cnt; p += 256) sidx[p] = csr2[s0 + p];
  __syncthreads();

  // segmented gather over this half-wave's contiguous 6-node edge slice
  const int hw = tid >> 5;  // 0..7: owns nodes [6hw, 6hw+6)
  const int gs = sstart[hw] - s0;
  const int ge = sstart[hw + 1] - s0;
  int cur = TROWS;  // scrap row
  float a0 = 0.f, a1 = 0.f;
  if (fast) {
    for (int p0 = gs; p0 < ge; p0 += 16) {
      u32 ev[16], v[16];
      LOADCHUNK(ev, v, p0)
      PROCCHUNK(ev, v)
    }
  } else {  // fallback (statistically never): stream straight from global csr2
    for (int p0 = gs; p0 < ge; p0 += 16) {
#pragma unroll
      for (int i = 0; i < 16; ++i) {
        int p = p0 + i;
        u32 ev = (p < ge) ? (u32)csr2[s0 + p] : DUMMY;
        u32 vv = xu[(size_t)(ev & 0x1FFFF) * 32 + fl];
        int n = (int)(ev >> 17);
        if (n != cur) {
          FLUSH(cur)
          cur = n; a0 = 0.f; a1 = 0.f;
        }
        a0 += blo(vv); a1 += bhi(vv);
      }
    }
  }
  FLUSH(cur)  // final (scrap row if slice empty)
  __syncthreads();  // gather slices span other waves' MFMA stripes

  // ---- MFMA MLP: waves 0-2 own stripes [16w, 16w+16); wave 3 idles ----
  const int lr = lane & 15;
  const int lg = lane >> 4;
  f32x4 acc[4];
  if (wvv < 3) {
    // GEMM1: h1 = relu(h_pre @ W1 + b1)
#pragma unroll
    for (int t = 0; t < 4; ++t) {
      float bv = b1[16 * t + lr];
      acc[t] = (f32x4){bv, bv, bv, bv};
    }
    mfma_gemm(tile32, wt1, wvv, lr, lg, acc);
    pack_relu(tile32, wvv, lr, lg, acc);

    // GEMM2: h2 = relu(h1 @ W2 + b2)
#pragma unroll
    for (int t = 0; t < 4; ++t) {
      float bv = b2[16 * t + lr];
      acc[t] = (f32x4){bv, bv, bv, bv};
    }
    mfma_gemm(tile32, wt2, wvv, lr, lg, acc);
    pack_relu(tile32, wvv, lr, lg, acc);

    if constexpr (FINAL == 0) {
      // own-stripe coalesced packed store
      u32* o32 = (u32*)outh;
#pragma unroll
      for (int rr = 0; rr < 8; ++rr) {
        int row = 16 * wvv + 2 * rr + h;
        if (row < rows) o32[(size_t)(base + row) * 32 + fl] = tile32[row * 33 + fl];
      }
    } else {
      // GEMM3: out(f32) = h2 @ Wf + bf (no relu), direct D-frag stores
#pragma unroll
      for (int t = 0; t < 4; ++t) {
        float bv = bf[16 * t + lr];
        acc[t] = (f32x4){bv, bv, bv, bv};
      }
      mfma_gemm(tile32, wtf, wvv, lr, lg, acc);
#pragma unroll
      for (int t = 0; t < 4; ++t)
#pragma unroll
        for (int r = 0; r < 4; ++r) {
          int row = 16 * wvv + 4 * lg + r;
          if (row < rows) outf[(size_t)(base + row) * 64 + 16 * t + lr] = acc[t][r];
        }
    }
  }
}

extern "C" void kernel_launch(void* const* d_in, const int* in_sizes, int n_in,
                              void* d_out, int out_size, void* d_ws, size_t ws_size,
                              hipStream_t stream) {
  const float* x   = (const float*)d_in[0];
  const int*   ei  = (const int*)d_in[1];
  const float* W1  = (const float*)d_in[2];
  const float* b1  = (const float*)d_in[3];
  const float* W2  = (const float*)d_in[4];
  const float* b2  = (const float*)d_in[5];
  const float* eps = (const float*)d_in[6];
  const float* Wf  = (const float*)d_in[7];
  const float* bf  = (const float*)d_in[8];

  // ws: xh0 | xh1 [NN*64 u16, 12.8MB each] | csr2[NE] | nstartP[NN+1]
  //     | Hmat[MH] | bsum[NSB2] | rstart[NR+1] | wt[7*2048 u32]  (~33.2 MB)
  u16* xh0 = (u16*)d_ws;
  u16* xh1 = xh0 + (size_t)NN * DIM;
  int* csr2    = (int*)(xh1 + (size_t)NN * DIM);
  int* nstartP = csr2 + NE;
  int* Hmat    = nstartP + NN + 1;
  int* bsum    = Hmat + MH;
  int* rstart  = bsum + NSB2;
  u32* wt      = (u32*)(rstart + NR + 1);
  // bb lives in d_out (dead until layer-2 k_gin writes the real output)
  int* bb = (int*)d_out;

  const int grid_conv = NN * DIM / 4 / 256;  // 6250, exact

  k_tobf<<<grid_conv, 256, 0, stream>>>(x, xh0);
  k_wconv<<<7, 256, 0, stream>>>(W1, W2, Wf, wt);
  k_phist<<<BP, 256, 0, stream>>>(ei, Hmat);
  k_sA<<<NSB2, 256, 0, stream>>>(Hmat, bsum);
  k_sB<<<1, 1024, 0, stream>>>(bsum);
  k_sC<<<NSB2, 256, 0, stream>>>(Hmat, bsum);
  k_rex<<<1, 512, 0, stream>>>(Hmat, rstart, nstartP);
  k_pfill<<<BP, 256, 0, stream>>>(ei, Hmat, bb);
  k_rsort<<<NR, 256, 0, stream>>>(rstart, bb, csr2, nstartP);

  // bf16 ping-pong: L0 xh0->xh1, L1 xh1->xh0, L2 xh0 -> (fused final) d_out f32
  k_gin<0><<<NTIL, 256, 0, stream>>>(xh0, nstartP, csr2, eps, 0,
                                     wt + 0 * 2048, b1, wt + 3 * 2048, b2,
                                     xh1, wt + 6 * 2048, bf, nullptr);
  k_gin<0><<<NTIL, 256, 0, stream>>>(xh1, nstartP, csr2, eps, 1,
                                     wt + 1 * 2048, b1 + 64, wt + 4 * 2048, b2 + 64,
                                     xh0, wt + 6 * 2048, bf, nullptr);
  k_gin<1><<<NTIL, 256, 0, stream>>>(xh0, nstartP, csr2, eps, 2,
                                     wt + 2 * 2048, b1 + 128, wt + 5 * 2048, b2 + 128,
                                     xh1, wt + 6 * 2048, bf, (float*)d_out);
}

// Round 22
// 204.844 us; speedup vs baseline: 1.0753x; 1.0753x over previous
//
#include <hip/hip_runtime.h>

#define NN 100000
#define NE 1600000
#define DIM 64
#define NR 391      // regions = ceil(NN/256), key = dst>>8
#define BP 400      // partition blocks, 4000 edges each
#define MH (NR * BP)  // 156400 histogram cells, r-major
#define NSB2 611    // ceil(MH/256)
#define IDXCAP 1664 // staged edge cap per 64-node tile (mean 1024, 20 sigma)
#define DUMMY (64u << 17)  // pad edge: src 0 (valid row), target scrap row 64

typedef unsigned short u16;
typedef unsigned int u32;
typedef __attribute__((ext_vector_type(8))) short short8;  // 8 bf16 (4 VGPRs)
typedef __attribute__((ext_vector_type(4))) float f32x4;

__device__ __forceinline__ u16 f2b(float f) {  // f32 -> bf16 RNE
  union { float f; u32 u; } c; c.f = f;
  u32 u = c.u;
  u += 0x7FFF + ((u >> 16) & 1);
  return (u16)(u >> 16);
}
__device__ __forceinline__ float blo(u32 v) {
  union { u32 u; float f; } c; c.u = v << 16;
  return c.f;
}
__device__ __forceinline__ float bhi(u32 v) {
  union { u32 u; float f; } c; c.u = v & 0xFFFF0000u;
  return c.f;
}
__device__ __forceinline__ u32 pk(float lo, float hi) {  // pack 2 bf16
  return ((u32)f2b(hi) << 16) | (u32)f2b(lo);
}

union FragU { u32 w[4]; short8 v; };

// x (f32) -> xh (bf16), 4 elems/thread, exact grid
__global__ __launch_bounds__(256) void k_tobf(const float* __restrict__ x,
                                              u16* __restrict__ xh) {
  int i = blockIdx.x * 256 + threadIdx.x;
  float4 v = ((const float4*)x)[i];
  ushort4 o;
  o.x = f2b(v.x); o.y = f2b(v.y); o.z = f2b(v.z); o.w = f2b(v.w);
  ((ushort4*)xh)[i] = o;
}

// convert 7 64x64 f32 weights ([k][j] k-major) -> bf16-packed transposed
// wt[m][j][kk] : u32 = {k=2kk (lo), k=2kk+1 (hi)} at column j.
__global__ __launch_bounds__(256) void k_wconv(const float* __restrict__ W1,
                                               const float* __restrict__ W2,
                                               const float* __restrict__ Wf,
                                               u32* __restrict__ wt) {
  int m = blockIdx.x;
  const float* src = (m < 3) ? (W1 + m * 4096) : (m < 6 ? (W2 + (m - 3) * 4096) : Wf);
  for (int c = threadIdx.x; c < 2048; c += 256) {
    int j = c >> 5, kk = c & 31;
    wt[m * 2048 + c] = pk(src[(2 * kk) * 64 + j], src[(2 * kk + 1) * 64 + j]);
  }
}

// ---- deterministic two-pass region partition (no global data atomics) ----

__global__ __launch_bounds__(256) void k_phist(const int* __restrict__ ei,
                                               int* __restrict__ Hmat) {
  __shared__ int lh[NR];
  const int t = threadIdx.x;
  const int b = blockIdx.x;
  for (int i = t; i < NR; i += 256) lh[i] = 0;
  __syncthreads();
  const int e0 = b * 4000;
  for (int k = 0; k < 16; ++k) {
    int o = k * 256 + t;
    if (o < 4000) atomicAdd(&lh[ei[NE + e0 + o] >> 8], 1);
  }
  __syncthreads();
  for (int i = t; i < NR; i += 256) Hmat[i * BP + b] = lh[i];
}

__global__ __launch_bounds__(256) void k_sA(int* __restrict__ a,
                                            int* __restrict__ bsum) {
  __shared__ int buf[256];
  const int t = threadIdx.x;
  const int i = blockIdx.x * 256 + t;
  int v = (i < MH) ? a[i] : 0;
  buf[t] = v;
  __syncthreads();
  for (int off = 1; off < 256; off <<= 1) {
    int u = (t >= off) ? buf[t - off] : 0;
    __syncthreads();
    buf[t] += u;
    __syncthreads();
  }
  if (i < MH) a[i] = buf[t] - v;
  if (t == 255) bsum[blockIdx.x] = buf[255];
}

__global__ __launch_bounds__(1024) void k_sB(int* __restrict__ bsum) {
  __shared__ int buf[1024];
  const int t = threadIdx.x;
  int v = (t < NSB2) ? bsum[t] : 0;
  buf[t] = v;
  __syncthreads();
  for (int off = 1; off < 1024; off <<= 1) {
    int u = (t >= off) ? buf[t - off] : 0;
    __syncthreads();
    buf[t] += u;
    __syncthreads();
  }
  if (t < NSB2) bsum[t] = buf[t] - v;
}

__global__ __launch_bounds__(256) void k_sC(int* __restrict__ a,
                                            const int* __restrict__ bsum) {
  int i = blockIdx.x * 256 + threadIdx.x;
  if (i < MH) a[i] += bsum[blockIdx.x];
}

__global__ __launch_bounds__(512) void k_rex(const int* __restrict__ Hs,
                                             int* __restrict__ rstart,
                                             int* __restrict__ nstartP) {
  int t = threadIdx.x;
  if (t < NR) rstart[t] = Hs[t * BP];
  if (t == 0) { rstart[NR] = NE; nstartP[NN] = NE; }
}

__global__ __launch_bounds__(256) void k_pfill(const int* __restrict__ ei,
                                               const int* __restrict__ Hs,
                                               int* __restrict__ bb) {
  __shared__ int lcur[NR];
  const int t = threadIdx.x;
  const int b = blockIdx.x;
  for (int i = t; i < NR; i += 256) lcur[i] = Hs[i * BP + b];
  __syncthreads();
  const int e0 = b * 4000;
  for (int k = 0; k < 16; ++k) {
    int o = k * 256 + t;
    if (o < 4000) {
      int e = e0 + o;
      int src = ei[e];
      int dst = ei[NE + e];
      int p = atomicAdd(&lcur[dst >> 8], 1);  // LDS atomic only
      bb[p] = src | ((dst & 255) << 17);      // src < 2^17
    }
  }
}

// counting-sort by node -> csr2 entries = src | (tile_local_node << 17)
__global__ __launch_bounds__(256) void k_rsort(const int* __restrict__ rstart,
                                               const int* __restrict__ bb,
                                               int* __restrict__ csr2,
                                               int* __restrict__ nstartP) {
  __shared__ int nhist[256], ncur[256], buf[256];
  const int t = threadIdx.x;
  const int r = blockIdx.x;
  const int s = rstart[r];
  const int cnt = rstart[r + 1] - s;
  const int nb = r << 8;
  nhist[t] = 0;
  __syncthreads();
  for (int p = t; p < cnt; p += 256) atomicAdd(&nhist[bb[s + p] >> 17], 1);
  __syncthreads();
  int v = nhist[t];
  buf[t] = v;
  __syncthreads();
  for (int off = 1; off < 256; off <<= 1) {
    int u = (t >= off) ? buf[t - off] : 0;
    __syncthreads();
    buf[t] += u;
    __syncthreads();
  }
  int st = s + buf[t] - v;
  ncur[t] = st;
  if (nb + t < NN) nstartP[nb + t] = st;
  __syncthreads();
  for (int p = t; p < cnt; p += 256) {
    int e2 = bb[s + p];
    int loc = e2 >> 17;  // node-in-region 0..255
    int pos = atomicAdd(&ncur[loc], 1);
    csr2[pos] = (e2 & 0x1FFFF) | ((loc & 63) << 17);  // tile-local tag
  }
}

// one 16x16x64 GEMM slice: wave's M-stripe x all 64 cols. A from packed LDS
// (u32 stride 33); B from bf16-packed transposed wt.
__device__ __forceinline__ void mfma_gemm(const u32* T32, const u32* __restrict__ wt,
                                          int wvv, int lr, int lg, f32x4 acc[4]) {
  FragU a0, a1;
  const int abase = (16 * wvv + lr) * 33 + 4 * lg;
#pragma unroll
  for (int c = 0; c < 4; ++c) { a0.w[c] = T32[abase + c]; a1.w[c] = T32[abase + 16 + c]; }
#pragma unroll
  for (int t = 0; t < 4; ++t) {
    FragU b0, b1;
    const u32* wp = wt + (16 * t + lr) * 32 + 4 * lg;
#pragma unroll
    for (int c = 0; c < 4; ++c) { b0.w[c] = wp[c]; b1.w[c] = wp[16 + c]; }
    acc[t] = __builtin_amdgcn_mfma_f32_16x16x32_bf16(a0.v, b0.v, acc[t], 0, 0, 0);
    acc[t] = __builtin_amdgcn_mfma_f32_16x16x32_bf16(a1.v, b1.v, acc[t], 0, 0, 0);
  }
}

// relu + pack D frags (col=lane&15, row=4*(lane>>4)+r) back into packed words
__device__ __forceinline__ void pack_relu(u32* T32, int wvv, int lr, int lg,
                                          const f32x4 acc[4]) {
#pragma unroll
  for (int t = 0; t < 4; ++t)
#pragma unroll
    for (int r = 0; r < 4; ++r) {
      float v = fmaxf(acc[t][r], 0.0f);
      float p = __shfl_xor(v, 1, 64);  // partner holds col^1, same rows
      if ((lr & 1) == 0)
        T32[(16 * wvv + 4 * lg + r) * 33 + 8 * t + (lr >> 1)] = pk(v, p);
    }
}

// load a 16-edge chunk: tags from staged LDS (DUMMY past end), then issue
// all 16 row-loads. Named register arrays, fully unrolled (static indexing).
#define LOADCHUNK(EV, VV, P0)                              \
  _Pragma("unroll")                                        \
  for (int i_ = 0; i_ < 16; ++i_) {                        \
    int p_ = (P0) + i_;                                    \
    EV[i_] = (p_ < ge) ? (u32)sidx[p_] : DUMMY;            \
  }                                                        \
  _Pragma("unroll")                                        \
  for (int i_ = 0; i_ < 16; ++i_)                          \
    VV[i_] = xu[(size_t)(EV[i_] & 0x1FFFF) * 32 + fl];

// flush: tile word = pk(sc*self + acc). One flush per node (sorted slice),
// so OVERWRITE with the full f32 sum -- same rounding count as an f32 tile.
#define FLUSH(CUR)                                          \
  {                                                         \
    float s0_ = 0.f, s1_ = 0.f;                             \
    if ((CUR) < rows) {                                     \
      u32 su_ = xu[(size_t)(base + (CUR)) * 32 + fl];       \
      s0_ = sc * blo(su_); s1_ = sc * bhi(su_);             \
    }                                                       \
    tile32[(CUR) * 33 + fl] = pk(s0_ + a0, s1_ + a1);       \
  }

#define PROCCHUNK(EV, VV)                                  \
  _Pragma("unroll")                                        \
  for (int i_ = 0; i_ < 16; ++i_) {                        \
    int n_ = (int)(EV[i_] >> 17);                          \
    if (n_ != cur) {                                       \
      FLUSH(cur)                                           \
      cur = n_; a0 = 0.f; a1 = 0.f;                        \
    }                                                      \
    a0 += blo(VV[i_]); a1 += bhi(VV[i_]);                  \
  }

// ---- fused layer: segmented flat-edge gather (register accumulation,
//      one packed-bf16 flush per node, own-stripe everywhere -> only ONE
//      barrier) -> MFMA MLP (+ fused final). LDS 15.3KB -> 8 blocks/CU. ----
template <int FINAL>
__global__ __launch_bounds__(256, 8) void k_gin(const u16* __restrict__ xh,
                                                const int* __restrict__ nstartP,
                                                const int* __restrict__ csr2,
                                                const float* __restrict__ eps, int l,
                                                const u32* __restrict__ wt1,
                                                const float* __restrict__ b1,
                                                const u32* __restrict__ wt2,
                                                const float* __restrict__ b2,
                                                u16* __restrict__ outh,
                                                const u32* __restrict__ wtf,
                                                const float* __restrict__ bf,
                                                float* __restrict__ outf) {
  __shared__ u32 tile32[65 * 33];  // packed bf16 pairs; row 64 = scrap
  __shared__ int sidx[IDXCAP];
  __shared__ int sstart[9];        // node-octet boundaries
  const int tid = threadIdx.x;
  const int lane = tid & 63;
  const int wvv = tid >> 6;  // 0..3
  const int h = lane >> 5;
  const int fl = lane & 31;
  const int base = blockIdx.x * 64;
  const int rows = min(64, NN - base);
  const float sc = 1.0f + eps[l];
  const u32* xu = (const u32*)xh;

  const int s0 = nstartP[base];
  const int cnt = nstartP[min(base + 64, NN)] - s0;
  if (tid < 9) sstart[tid] = nstartP[min(base + 8 * tid, NN)];
  const bool fast = (cnt <= IDXCAP);

  // init own-stripe: tile word = pk(sc*self); overwritten at flush for nodes
  // with edges; survives for isolated nodes.
#pragma unroll
  for (int c = 0; c < 8; ++c) {
    int row = 16 * wvv + 2 * c + h;
    u32 w = 0;
    if (row < rows) {
      u32 u_ = xu[(size_t)(base + row) * 32 + fl];
      w = pk(sc * blo(u_), sc * bhi(u_));
    }
    tile32[row * 33 + fl] = w;
  }
  if (fast)
    for (int p = tid; p < cnt; p += 256) sidx[p] = csr2[s0 + p];
  __syncthreads();  // sidx + sstart visible (tile is own-stripe)

  // segmented gather over this half-wave's contiguous edge slice
  const int hw = wvv * 2 + h;  // 0..7: owns nodes [8hw, 8hw+8)
  const int gs = sstart[hw] - s0;
  const int ge = sstart[hw + 1] - s0;
  int cur = 64;  // scrap row
  float a0 = 0.f, a1 = 0.f;
  if (fast) {
    for (int p0 = gs; p0 < ge; p0 += 16) {
      u32 ev[16], v[16];
      LOADCHUNK(ev, v, p0)
      PROCCHUNK(ev, v)
    }
  } else {  // fallback (statistically never): stream straight from global csr2
    for (int p0 = gs; p0 < ge; p0 += 16) {
#pragma unroll
      for (int i = 0; i < 16; ++i) {
        int p = p0 + i;
        u32 ev = (p < ge) ? (u32)csr2[s0 + p] : DUMMY;
        u32 vv = xu[(size_t)(ev & 0x1FFFF) * 32 + fl];
        int n = (int)(ev >> 17);
        if (n != cur) {
          FLUSH(cur)
          cur = n; a0 = 0.f; a1 = 0.f;
        }
        a0 += blo(vv); a1 += bhi(vv);
      }
    }
  }
  FLUSH(cur)  // final (scrap row if slice empty)
  // no barrier: gather wrote only this wave's 16-row stripe (+ scrap, unread);
  // the MLP below also reads only the own stripe.

  const int lr = lane & 15;
  const int lg = lane >> 4;
  f32x4 acc[4];

  // GEMM1: h1 = relu(h_pre @ W1 + b1)
#pragma unroll
  for (int t = 0; t < 4; ++t) {
    float bv = b1[16 * t + lr];
    acc[t] = (f32x4){bv, bv, bv, bv};
  }
  mfma_gemm(tile32, wt1, wvv, lr, lg, acc);
  pack_relu(tile32, wvv, lr, lg, acc);

  // GEMM2: h2 = relu(h1 @ W2 + b2)
#pragma unroll
  for (int t = 0; t < 4; ++t) {
    float bv = b2[16 * t + lr];
    acc[t] = (f32x4){bv, bv, bv, bv};
  }
  mfma_gemm(tile32, wt2, wvv, lr, lg, acc);
  pack_relu(tile32, wvv, lr, lg, acc);

  if constexpr (FINAL == 0) {
    // own-stripe coalesced packed store
    u32* o32 = (u32*)outh;
#pragma unroll
    for (int rr = 0; rr < 8; ++rr) {
      int row = 16 * wvv + 2 * rr + h;
      if (row < rows) o32[(size_t)(base + row) * 32 + fl] = tile32[row * 33 + fl];
    }
  } else {
    // GEMM3: out(f32) = h2 @ Wf + bf (no relu), direct D-frag stores
#pragma unroll
    for (int t = 0; t < 4; ++t) {
      float bv = bf[16 * t + lr];
      acc[t] = (f32x4){bv, bv, bv, bv};
    }
    mfma_gemm(tile32, wtf, wvv, lr, lg, acc);
#pragma unroll
    for (int t = 0; t < 4; ++t)
#pragma unroll
      for (int r = 0; r < 4; ++r) {
        int row = 16 * wvv + 4 * lg + r;
        if (row < rows) outf[(size_t)(base + row) * 64 + 16 * t + lr] = acc[t][r];
      }
  }
}

extern "C" void kernel_launch(void* const* d_in, const int* in_sizes, int n_in,
                              void* d_out, int out_size, void* d_ws, size_t ws_size,
                              hipStream_t stream) {
  const float* x   = (const float*)d_in[0];
  const int*   ei  = (const int*)d_in[1];
  const float* W1  = (const float*)d_in[2];
  const float* b1  = (const float*)d_in[3];
  const float* W2  = (const float*)d_in[4];
  const float* b2  = (const float*)d_in[5];
  const float* eps = (const float*)d_in[6];
  const float* Wf  = (const float*)d_in[7];
  const float* bf  = (const float*)d_in[8];

  // ws: xh0 | xh1 [NN*64 u16, 12.8MB each] | csr2[NE] | nstartP[NN+1]
  //     | Hmat[MH] | bsum[NSB2] | rstart[NR+1] | wt[7*2048 u32]  (~33.2 MB)
  u16* xh0 = (u16*)d_ws;
  u16* xh1 = xh0 + (size_t)NN * DIM;
  int* csr2    = (int*)(xh1 + (size_t)NN * DIM);
  int* nstartP = csr2 + NE;
  int* Hmat    = nstartP + NN + 1;
  int* bsum    = Hmat + MH;
  int* rstart  = bsum + NSB2;
  u32* wt      = (u32*)(rstart + NR + 1);
  // bb lives in d_out (dead until layer-2 k_gin writes the real output)
  int* bb = (int*)d_out;

  const int grid_conv = NN * DIM / 4 / 256;  // 6250, exact
  const int grid_mlp  = (NN + 63) / 64;      // 1563

  k_tobf<<<grid_conv, 256, 0, stream>>>(x, xh0);
  k_wconv<<<7, 256, 0, stream>>>(W1, W2, Wf, wt);
  k_phist<<<BP, 256, 0, stream>>>(ei, Hmat);
  k_sA<<<NSB2, 256, 0, stream>>>(Hmat, bsum);
  k_sB<<<1, 1024, 0, stream>>>(bsum);
  k_sC<<<NSB2, 256, 0, stream>>>(Hmat, bsum);
  k_rex<<<1, 512, 0, stream>>>(Hmat, rstart, nstartP);
  k_pfill<<<BP, 256, 0, stream>>>(ei, Hmat, bb);
  k_rsort<<<NR, 256, 0, stream>>>(rstart, bb, csr2, nstartP);

  // bf16 ping-pong: L0 xh0->xh1, L1 xh1->xh0, L2 xh0 -> (fused final) d_out f32
  k_gin<0><<<grid_mlp, 256, 0, stream>>>(xh0, nstartP, csr2, eps, 0,
                                         wt + 0 * 2048, b1, wt + 3 * 2048, b2,
                                         xh1, wt + 6 * 2048, bf, nullptr);
  k_gin<0><<<grid_mlp, 256, 0, stream>>>(xh1, nstartP, csr2, eps, 1,
                                         wt + 1 * 2048, b1 + 64, wt + 4 * 2048, b2 + 64,
                                         xh0, wt + 6 * 2048, bf, nullptr);
  k_gin<1><<<grid_mlp, 256, 0, stream>>>(xh0, nstartP, csr2, eps, 2,
                                         wt + 2 * 2048, b1 + 128, wt + 5 * 2048, b2 + 128,
                                         xh1, wt + 6 * 2048, bf, (float*)d_out);
}